// Round 9
// baseline (1385.245 us; speedup 1.0000x reference)
//
#include <hip/hip_runtime.h>
#include <math.h>

// Problem constants (setup_inputs): B=2, T=2048, E=2048, H=16, hd=128
#define TT 2048
#define EE 2048
#define NH 16
#define HD 128
#define MM 4096   // B*T
#define GK 2048   // K dim of all GEMMs

using f32x4  = __attribute__((ext_vector_type(4))) float;
using bf16x8 = __attribute__((ext_vector_type(8))) short;

#define MFMA16(a, b, c) __builtin_amdgcn_mfma_f32_16x16x32_bf16(a, b, c, 0, 0, 0)

// round-to-nearest-even fp32 -> bf16 (bit pattern in ushort)
__device__ __forceinline__ ushort bf_hi(float x) {
    uint u = __float_as_uint(x);
    uint r = (u + 0x7fffu + ((u >> 16) & 1u)) >> 16;
    return (ushort)r;
}
__device__ __forceinline__ float bf_f(ushort h) {
    return __uint_as_float(((uint)h) << 16);
}

// async global->LDS 16B: per-lane global src, wave-uniform LDS base + lane*16
__device__ __forceinline__ void gload16(const void* g, void* l) {
    __builtin_amdgcn_global_load_lds((const __attribute__((address_space(1))) void*)g,
                                     (__attribute__((address_space(3))) void*)l, 16, 0, 0);
}

// ---------------------------------------------------------------------------
// split_x: fp32 -> bf16 hi/lo arrays (same layout). 4 elems/thread.
// ---------------------------------------------------------------------------
__global__ __launch_bounds__(256)
void split_x(const float* __restrict__ x, ushort* __restrict__ xh,
             ushort* __restrict__ xl)
{
    int idx = (blockIdx.x * 256 + threadIdx.x) * 4;
    float4 v = *(const float4*)&x[idx];
    float f[4] = {v.x, v.y, v.z, v.w};
    ushort h[4], l[4];
#pragma unroll
    for (int e = 0; e < 4; ++e) {
        h[e] = bf_hi(f[e]);
        l[e] = bf_hi(f[e] - bf_f(h[e]));
    }
    *(ushort4*)&xh[idx] = make_ushort4(h[0], h[1], h[2], h[3]);
    *(ushort4*)&xl[idx] = make_ushort4(l[0], l[1], l[2], l[3]);
}

// ---------------------------------------------------------------------------
// tw_prep: W [2048 k][ldw cols] fp32, cols [c0,c0+2048) -> Wt_hi/lo [n][k] bf16
// ---------------------------------------------------------------------------
__global__ __launch_bounds__(256)
void tw_prep(const float* __restrict__ W, int ldw, int c0,
             ushort* __restrict__ th, ushort* __restrict__ tl)
{
    __shared__ float tile[32][33];
    const int k0 = blockIdx.x * 32, n0 = blockIdx.y * 32;
    const int tx = threadIdx.x & 31, ty = threadIdx.x >> 5;   // 32 x 8
#pragma unroll
    for (int j = 0; j < 4; ++j)
        tile[ty + 8 * j][tx] = W[(size_t)(k0 + ty + 8 * j) * ldw + c0 + n0 + tx];
    __syncthreads();
#pragma unroll
    for (int j = 0; j < 4; ++j) {
        float v = tile[tx][ty + 8 * j];
        ushort h = bf_hi(v);
        ushort l = bf_hi(v - bf_f(h));
        size_t off = (size_t)(n0 + ty + 8 * j) * GK + k0 + tx;
        th[off] = h;
        tl[off] = l;
    }
}

// ---------------------------------------------------------------------------
// Split-bf16 MFMA GEMM (round-6 validated, unchanged).
// ---------------------------------------------------------------------------
template <int SCATTER>
__global__ __launch_bounds__(256)
void gemm_bf16(const ushort* __restrict__ Ah, const ushort* __restrict__ Al,
               const ushort* __restrict__ Bh, const ushort* __restrict__ Bl,
               float* __restrict__ out)
{
    __shared__ ushort AhS[4096], AlS[4096], BhS[4096], BlS[4096];  // [128][32] each

    const int tid  = threadIdx.x;
    const int wid  = tid >> 6;
    const int lane = tid & 63;
    const int lh   = lane >> 4;
    const int j16  = lane & 15;
    const int wm   = wid >> 1, wn = wid & 1;
    const int bm   = blockIdx.y * 128, bn = blockIdx.x * 128;

    const int g0 = wid * 128 + lane;
    const int g1 = g0 + 64;
    const int r0 = g0 >> 2, o0 = (g0 & 3) ^ (r0 & 3);
    const int r1 = g1 >> 2, o1 = (g1 & 3) ^ (r1 & 3);
    const size_t sa0 = (size_t)(bm + r0) * GK + o0 * 8;
    const size_t sa1 = (size_t)(bm + r1) * GK + o1 * 8;
    const size_t sb0 = (size_t)(bn + r0) * GK + o0 * 8;
    const size_t sb1 = (size_t)(bn + r1) * GK + o1 * 8;
    const ushort* a0h = Ah + sa0; const ushort* a1h = Ah + sa1;
    const ushort* a0l = Al + sa0; const ushort* a1l = Al + sa1;
    const ushort* b0h = Bh + sb0; const ushort* b1h = Bh + sb1;
    const ushort* b0l = Bl + sb0; const ushort* b1l = Bl + sb1;
    const int lds0 = wid * 1024;
    const int lds1 = wid * 1024 + 512;

    const int swz = (lh ^ (j16 & 3)) * 8;
    int offA[4], offB[4];
#pragma unroll
    for (int i = 0; i < 4; ++i) {
        offA[i] = (wm * 64 + i * 16 + j16) * 32 + swz;
        offB[i] = (wn * 64 + i * 16 + j16) * 32 + swz;
    }

    f32x4 acc[4][4];
#pragma unroll
    for (int i = 0; i < 4; ++i)
#pragma unroll
        for (int j = 0; j < 4; ++j)
#pragma unroll
            for (int e = 0; e < 4; ++e) acc[i][j][e] = 0.f;

    for (int kt = 0; kt < GK; kt += 32) {
        __syncthreads();
        gload16(a0h + kt, &AhS[lds0]);
        gload16(a1h + kt, &AhS[lds1]);
        gload16(a0l + kt, &AlS[lds0]);
        gload16(a1l + kt, &AlS[lds1]);
        gload16(b0h + kt, &BhS[lds0]);
        gload16(b1h + kt, &BhS[lds1]);
        gload16(b0l + kt, &BlS[lds0]);
        gload16(b1l + kt, &BlS[lds1]);
        __syncthreads();

        bf16x8 ah[4], al[4], bh[4], bl[4];
#pragma unroll
        for (int i = 0; i < 4; ++i) {
            ah[i] = *(const bf16x8*)&AhS[offA[i]];
            al[i] = *(const bf16x8*)&AlS[offA[i]];
            bh[i] = *(const bf16x8*)&BhS[offB[i]];
            bl[i] = *(const bf16x8*)&BlS[offB[i]];
        }
#pragma unroll
        for (int i = 0; i < 4; ++i)
#pragma unroll
            for (int j = 0; j < 4; ++j) {
                acc[i][j] = MFMA16(ah[i], bh[j], acc[i][j]);
                acc[i][j] = MFMA16(ah[i], bl[j], acc[i][j]);
                acc[i][j] = MFMA16(al[i], bh[j], acc[i][j]);
            }
    }

#pragma unroll
    for (int i = 0; i < 4; ++i)
#pragma unroll
        for (int j = 0; j < 4; ++j) {
            const int n = bn + wn * 64 + j * 16 + j16;
#pragma unroll
            for (int e = 0; e < 4; ++e) {
                const int m = bm + wm * 64 + i * 16 + 4 * lh + e;
                if (SCATTER) {
                    const int h = n >> 7, d = n & 127;
                    const int b = m >> 11, t = m & 2047;
                    out[(((size_t)b * NH + h) * TT + t) * HD + d] = acc[i][j][e];
                } else {
                    out[(size_t)m * EE + n] = acc[i][j][e];
                }
            }
        }
}

// ---------------------------------------------------------------------------
// RoPE: q fp32 in-place; k fp32 -> rotated bf16 hi/lo (KH/KL, same layout).
// ---------------------------------------------------------------------------
__global__ __launch_bounds__(256)
void rope_split(float* __restrict__ q, const float* __restrict__ k,
                ushort* __restrict__ kh, ushort* __restrict__ kl)
{
    int idx = blockIdx.x * 256 + threadIdx.x;
    int j = idx & 63;
    int row = idx >> 6;
    int t = row & (TT - 1);
    float inv = __expf((float)(2 * j) * (-9.210340371976184f / 128.0f));
    float ang = (float)t * inv;
    float s, c;
    sincosf(ang, &s, &c);
    size_t base = (size_t)row * HD;
    float q0 = q[base + j], q1 = q[base + j + 64];
    q[base + j]      = q0 * c - q1 * s;
    q[base + j + 64] = q1 * c + q0 * s;
    float k0 = k[base + j], k1 = k[base + j + 64];
    float ka = k0 * c - k1 * s;
    float kb = k1 * c + k0 * s;
    ushort ha = bf_hi(ka), hb = bf_hi(kb);
    kh[base + j]      = ha;  kl[base + j]      = bf_hi(ka - bf_f(ha));
    kh[base + j + 64] = hb;  kl[base + j + 64] = bf_hi(kb - bf_f(hb));
}

// ---------------------------------------------------------------------------
// Transpose+split V [B,H,T,128] fp32 -> VtH/VtL [B,H,128,T] bf16.
// ---------------------------------------------------------------------------
__global__ __launch_bounds__(256)
void transpose_split(const float* __restrict__ v, ushort* __restrict__ vth,
                     ushort* __restrict__ vtl)
{
    __shared__ float tile[32][33];
    const int bh = blockIdx.z;
    const int t0 = blockIdx.x * 32, d0 = blockIdx.y * 32;
    const int tx = threadIdx.x & 31, ty = threadIdx.x >> 5;
#pragma unroll
    for (int j = 0; j < 4; ++j)
        tile[ty + 8 * j][tx] = v[((size_t)bh * TT + t0 + ty + 8 * j) * HD + d0 + tx];
    __syncthreads();
#pragma unroll
    for (int j = 0; j < 4; ++j) {
        float val = tile[tx][ty + 8 * j];
        size_t off = ((size_t)bh * HD + d0 + ty + 8 * j) * TT + t0 + tx;
        ushort h = bf_hi(val);
        vth[off] = h;
        vtl[off] = bf_hi(val - bf_f(h));
    }
}

// ---------------------------------------------------------------------------
// MFMA flash attention v2, split-bf16, pre-split K/Vt inputs.
// Block 256 = 4 waves; QBLK=128 (32 q-rows/wave, 2 row-groups g), KVBLK=64.
// LDS tiles (granule = 16B, phys_granule = logical ^ (row&7)):
//   KhS/KlS [64 key][128 dim], VhS/VlS [128 dim][64 key].  65.5 KB total.
// After the mid-tile barrier the K tile is dead; per-wave P[32 q][64 key]
// hi/lo aliases KhS/KlS (wave chunk = wid*2048 ushorts).
// Staging: pure global_load_lds dwordx4 with pre-swizzled per-lane source.
// 3 barriers / 64-key tile. 192 MFMA : 72 ds_read_b128 per tile per wave.
// Output: bf16 hi/lo [B,T,E] (feeds proj GEMM).
// ---------------------------------------------------------------------------
__global__ __launch_bounds__(256, 2)
void attn_mfma2(const float* __restrict__ Q,
                const ushort* __restrict__ KH, const ushort* __restrict__ KL,
                const ushort* __restrict__ VH, const ushort* __restrict__ VL,
                const int* __restrict__ am,
                ushort* __restrict__ oh, ushort* __restrict__ ol)
{
    __shared__ ushort KhS[8192];   // K hi; after B2: per-wave P hi
    __shared__ ushort KlS[8192];   // K lo; after B2: per-wave P lo
    __shared__ ushort VhS[8192];   // Vt hi [128][64]
    __shared__ ushort VlS[8192];   // Vt lo
    __shared__ float  cor[4][32], lsum[4][32];

    const int tid  = threadIdx.x;
    const int wid  = tid >> 6;
    const int lane = tid & 63;
    const int lh   = lane >> 4;
    const int j16  = lane & 15;

    const int qt = (int)gridDim.x - 1 - (int)blockIdx.x;   // big blocks first
    const int bh = blockIdx.y;
    const int bb = bh >> 4, hh = bh & 15;
    const int q0 = qt * 128;
    const int ntiles = 2 * qt + 2;

    // staging per-lane constants (phys granule p -> logical row/granule)
    int krow[4], kgl[4], vrow[4], vgl[4];
#pragma unroll
    for (int j = 0; j < 4; ++j) {
        int p = wid * 256 + j * 64 + lane;
        krow[j] = p >> 4; kgl[j] = (p & 15) ^ (krow[j] & 7);
        vrow[j] = p >> 3; vgl[j] = (p & 7)  ^ (vrow[j] & 7);
    }
    const ushort* KHb = KH + (size_t)bh * TT * HD;
    const ushort* KLb = KL + (size_t)bh * TT * HD;
    const ushort* VHb = VH + (size_t)bh * HD * TT;
    const ushort* VLb = VL + (size_t)bh * HD * TT;

    // ---- Q fragments (pre-scaled), bf16 hi/lo, 2 row-groups ----
    const float scale = 0.08838834764831843f;
    bf16x8 qhf[2][4], qlf[2][4];
#pragma unroll
    for (int g = 0; g < 2; ++g) {
        const float* qrow = Q + ((size_t)bh * TT + q0 + wid * 32 + g * 16 + j16) * HD;
#pragma unroll
        for (int kc = 0; kc < 4; ++kc) {
            float4 a = *(const float4*)(qrow + kc * 32 + lh * 8);
            float4 b = *(const float4*)(qrow + kc * 32 + lh * 8 + 4);
            float f[8] = {a.x, a.y, a.z, a.w, b.x, b.y, b.z, b.w};
#pragma unroll
            for (int e = 0; e < 8; ++e) {
                float x = f[e] * scale;
                ushort hv = bf_hi(x);
                ushort lv = bf_hi(x - bf_f(hv));
                qhf[g][kc][e] = (short)hv;
                qlf[g][kc][e] = (short)lv;
            }
        }
    }
    int qmk[2][4];
#pragma unroll
    for (int g = 0; g < 2; ++g)
#pragma unroll
        for (int r = 0; r < 4; ++r)
            qmk[g][r] = am[bb * TT + q0 + wid * 32 + g * 16 + 4 * lh + r];

    float m_run[2][4], l_run[2][4];
#pragma unroll
    for (int g = 0; g < 2; ++g)
#pragma unroll
        for (int r = 0; r < 4; ++r) { m_run[g][r] = -3e38f; l_run[g][r] = 0.f; }
    f32x4 acc[8][2];
#pragma unroll
    for (int dt = 0; dt < 8; ++dt)
#pragma unroll
        for (int cg = 0; cg < 2; ++cg)
#pragma unroll
            for (int e = 0; e < 4; ++e) acc[dt][cg][e] = 0.f;

    ushort* PH = &KhS[wid * 2048];
    ushort* PL = &KlS[wid * 2048];

    for (int kt = 0; kt < ntiles; ++kt) {
        const int kv0 = kt * 64;
        int km[4];
#pragma unroll
        for (int kg = 0; kg < 4; ++kg)
            km[kg] = am[bb * TT + kv0 + kg * 16 + j16];

        // ---- stage K and Vt tiles (pure async copies, pre-swizzled src) ----
#pragma unroll
        for (int j = 0; j < 4; ++j) {
            const int gb = (wid * 256 + j * 64) * 8;   // ushort idx of granule base
            gload16(KHb + (size_t)(kv0 + krow[j]) * HD + kgl[j] * 8, &KhS[gb]);
            gload16(KLb + (size_t)(kv0 + krow[j]) * HD + kgl[j] * 8, &KlS[gb]);
            gload16(VHb + (size_t)vrow[j] * TT + kv0 + vgl[j] * 8,   &VhS[gb]);
            gload16(VLb + (size_t)vrow[j] * TT + kv0 + vgl[j] * 8,   &VlS[gb]);
        }
        __syncthreads();   // B1: tiles visible

        // ---- QK^T: 3-term split, 2 row-groups x 4 key-groups ----
        f32x4 s[2][4];
#pragma unroll
        for (int g = 0; g < 2; ++g)
#pragma unroll
            for (int kg = 0; kg < 4; ++kg)
#pragma unroll
                for (int e = 0; e < 4; ++e) s[g][kg][e] = 0.f;
#pragma unroll
        for (int kc = 0; kc < 4; ++kc) {
#pragma unroll
            for (int kg = 0; kg < 4; ++kg) {
                const int idx = (kg * 16 + j16) * 128 + (((kc * 4 + lh) ^ (j16 & 7)) * 8);
                bf16x8 kh = *(const bf16x8*)&KhS[idx];
                bf16x8 kl = *(const bf16x8*)&KlS[idx];
#pragma unroll
                for (int g = 0; g < 2; ++g) {
                    s[g][kg] = MFMA16(qhf[g][kc], kh, s[g][kg]);
                    s[g][kg] = MFMA16(qhf[g][kc], kl, s[g][kg]);
                    s[g][kg] = MFMA16(qlf[g][kc], kh, s[g][kg]);
                }
            }
        }

        // ---- online softmax (registers + shfl only) ----
        float pv[2][4][4], corr[2][4];
#pragma unroll
        for (int g = 0; g < 2; ++g)
#pragma unroll
            for (int r = 0; r < 4; ++r) {
                const int qg = q0 + wid * 32 + g * 16 + 4 * lh + r;
                float x[4];
                float tmax = -3e38f;
#pragma unroll
                for (int kg = 0; kg < 4; ++kg) {
                    const int key = kv0 + kg * 16 + j16;
                    float xx = s[g][kg][r];
                    if ((key > qg) | (km[kg] == 0) | (qmk[g][r] == 0)) xx = -1e9f;
                    x[kg] = xx;
                    tmax = fmaxf(tmax, xx);
                }
                tmax = fmaxf(tmax, __shfl_xor(tmax, 1));
                tmax = fmaxf(tmax, __shfl_xor(tmax, 2));
                tmax = fmaxf(tmax, __shfl_xor(tmax, 4));
                tmax = fmaxf(tmax, __shfl_xor(tmax, 8));
                float mnew = fmaxf(m_run[g][r], tmax);
                corr[g][r] = __expf(m_run[g][r] - mnew);
                m_run[g][r] = mnew;
                float psum = 0.f;
#pragma unroll
                for (int kg = 0; kg < 4; ++kg) {
                    pv[g][r][kg] = __expf(x[kg] - mnew);
                    psum += pv[g][r][kg];
                }
                psum += __shfl_xor(psum, 1);
                psum += __shfl_xor(psum, 2);
                psum += __shfl_xor(psum, 4);
                psum += __shfl_xor(psum, 8);
                l_run[g][r] = l_run[g][r] * corr[g][r] + psum;
                if (j16 == 0) cor[wid][g * 16 + 4 * lh + r] = corr[g][r];
            }

        __syncthreads();   // B2: all QK reads done; K LDS reusable as P

        // ---- P -> bf16 hi/lo into per-wave chunk of KhS/KlS ----
#pragma unroll
        for (int g = 0; g < 2; ++g)
#pragma unroll
            for (int r = 0; r < 4; ++r) {
                const int q = g * 16 + 4 * lh + r;
#pragma unroll
                for (int kg = 0; kg < 4; ++kg) {
                    const int glog = kg * 2 + (j16 >> 3);
                    const int idx = q * 64 + ((glog ^ (q & 7)) * 8) + (j16 & 7);
                    float p = pv[g][r][kg];
                    ushort h = bf_hi(p);
                    PH[idx] = h;
                    PL[idx] = bf_hi(p - bf_f(h));
                }
            }

        // ---- rescale O^T (intra-wave cor) ----
        const float cq0 = cor[wid][j16];
        const float cq1 = cor[wid][16 + j16];
#pragma unroll
        for (int dt = 0; dt < 8; ++dt)
#pragma unroll
            for (int e = 0; e < 4; ++e) {
                acc[dt][0][e] *= cq0;
                acc[dt][1][e] *= cq1;
            }

        // ---- PV: O^T += Vt * P^T, 2 key-chunks x 2 col-groups ----
#pragma unroll
        for (int c = 0; c < 2; ++c) {
            bf16x8 pbh0, pbl0, pbh1, pbl1;
            {
                const int p0 = (j16) * 64 + (((c * 4 + lh) ^ (j16 & 7)) * 8);
                const int p1 = (16 + j16) * 64 + (((c * 4 + lh) ^ (j16 & 7)) * 8);
                pbh0 = *(const bf16x8*)&PH[p0];
                pbl0 = *(const bf16x8*)&PL[p0];
                pbh1 = *(const bf16x8*)&PH[p1];
                pbl1 = *(const bf16x8*)&PL[p1];
            }
#pragma unroll
            for (int dt = 0; dt < 8; ++dt) {
                const int vidx = (dt * 16 + j16) * 64 + (((c * 4 + lh) ^ (j16 & 7)) * 8);
                bf16x8 vh = *(const bf16x8*)&VhS[vidx];
                bf16x8 vl = *(const bf16x8*)&VlS[vidx];
                acc[dt][0] = MFMA16(vh, pbh0, acc[dt][0]);
                acc[dt][0] = MFMA16(vh, pbl0, acc[dt][0]);
                acc[dt][0] = MFMA16(vl, pbh0, acc[dt][0]);
                acc[dt][1] = MFMA16(vh, pbh1, acc[dt][1]);
                acc[dt][1] = MFMA16(vh, pbl1, acc[dt][1]);
                acc[dt][1] = MFMA16(vl, pbh1, acc[dt][1]);
            }
        }
        __syncthreads();   // B3: P/V reads done before next staging
    }

    // ---- epilogue: 1/l, store bf16 hi/lo [B,T,E] ----
    if (j16 == 0) {
#pragma unroll
        for (int g = 0; g < 2; ++g)
#pragma unroll
            for (int r = 0; r < 4; ++r)
                lsum[wid][g * 16 + 4 * lh + r] = l_run[g][r];
    }
#pragma unroll
    for (int cg = 0; cg < 2; ++cg) {
        const float lv = lsum[wid][cg * 16 + j16];
        const float linv = (lv > 0.f) ? (1.f / lv) : 0.f;
        const int qg = q0 + wid * 32 + cg * 16 + j16;
        const size_t ob = ((size_t)bb * TT + qg) * EE + hh * HD;
#pragma unroll
        for (int dt = 0; dt < 8; ++dt) {
            ushort h[4], l[4];
#pragma unroll
            for (int e = 0; e < 4; ++e) {
                float v = acc[dt][cg][e] * linv;
                h[e] = bf_hi(v);
                l[e] = bf_hi(v - bf_f(h[e]));
            }
            *(ushort4*)&oh[ob + dt * 16 + 4 * lh] = make_ushort4(h[0], h[1], h[2], h[3]);
            *(ushort4*)&ol[ob + dt * 16 + 4 * lh] = make_ushort4(l[0], l[1], l[2], l[3]);
        }
    }
}

// ---------------------------------------------------------------------------
extern "C" void kernel_launch(void* const* d_in, const int* in_sizes, int n_in,
                              void* d_out, int out_size, void* d_ws, size_t ws_size,
                              hipStream_t stream)
{
    (void)in_sizes; (void)n_in; (void)out_size; (void)ws_size;
    const float* x     = (const float*)d_in[0];
    const int*   amask = (const int*)d_in[1];
    const float* Wqkv  = (const float*)d_in[2];
    const float* Wproj = (const float*)d_in[3];
    float* out = (float*)d_out;

    char* ws = (char*)d_ws;
    const size_t MB = 1024 * 1024;
    // Workspace schedule (144 MB, proven available in round 6):
    //  [0,32)   q fp32 (rope'd in place)
    //  [32,64)  k fp32 -> dead after rope -> VtH@32, VtL@48 (bf16)
    //  [64,96)  v fp32 -> dead after transpose -> ah@64, al@80 (bf16)
    //  [96,128) xh/xl  -> dead after QKV gemms -> KH@96, KL@112 (bf16)
    //  [128,144) wth/wtl (per-slice transposed weights)
    float*  q   = (float*)(ws + 0 * MB);
    float*  k   = (float*)(ws + 32 * MB);
    float*  v   = (float*)(ws + 64 * MB);
    ushort* vth = (ushort*)(ws + 32 * MB);
    ushort* vtl = (ushort*)(ws + 48 * MB);
    ushort* ah  = (ushort*)(ws + 64 * MB);
    ushort* al  = (ushort*)(ws + 80 * MB);
    ushort* xh  = (ushort*)(ws + 96 * MB);
    ushort* xl  = (ushort*)(ws + 112 * MB);
    ushort* kh  = (ushort*)(ws + 96 * MB);
    ushort* kl  = (ushort*)(ws + 112 * MB);
    ushort* wth = (ushort*)(ws + 128 * MB);
    ushort* wtl = (ushort*)(ws + 136 * MB);

    // 1) x -> bf16 hi/lo
    split_x<<<(MM * EE) / (256 * 4), 256, 0, stream>>>(x, xh, xl);

    // 2) per-slice: transpose+split weight, then MFMA GEMM -> q/k/v fp32
    float* qkv[3] = {q, k, v};
    for (int s = 0; s < 3; ++s) {
        tw_prep<<<dim3(GK / 32, EE / 32), 256, 0, stream>>>(
            Wqkv, 3 * EE, s * EE, wth, wtl);
        gemm_bf16<1><<<dim3(EE / 128, MM / 128), 256, 0, stream>>>(
            xh, xl, wth, wtl, qkv[s]);
    }

    // 3) RoPE: q in place; k -> KH/KL bf16 (xh/xl dead)
    rope_split<<<(MM * NH * 64) / 256, 256, 0, stream>>>(q, k, kh, kl);

    // 4) V -> VtH/VtL bf16 [B,H,128,T] (k dead)
    transpose_split<<<dim3(TT / 32, HD / 32, 2 * NH), 256, 0, stream>>>(v, vth, vtl);

    // 5) proj weight prep
    tw_prep<<<dim3(GK / 32, EE / 32), 256, 0, stream>>>(Wproj, EE, 0, wth, wtl);

    // 6) attention -> bf16 hi/lo (v dead)
    attn_mfma2<<<dim3(TT / 128, 2 * NH), 256, 0, stream>>>(
        q, kh, kl, vth, vtl, amask, ah, al);

    // 7) out projection
    gemm_bf16<0><<<dim3(EE / 128, MM / 128), 256, 0, stream>>>(
        ah, al, wth, wtl, out);
}

// Round 10
// 834.281 us; speedup vs baseline: 1.6604x; 1.6604x over previous
//
#include <hip/hip_runtime.h>
#include <math.h>

// Problem constants (setup_inputs): B=2, T=2048, E=2048, H=16, hd=128
#define TT 2048
#define EE 2048
#define NH 16
#define HD 128
#define MM 4096   // B*T
#define GK 2048   // K dim of all GEMMs

using f32x4  = __attribute__((ext_vector_type(4))) float;
using bf16x8 = __attribute__((ext_vector_type(8))) short;

#define MFMA16(a, b, c) __builtin_amdgcn_mfma_f32_16x16x32_bf16(a, b, c, 0, 0, 0)

// round-to-nearest-even fp32 -> bf16 (bit pattern in ushort)
__device__ __forceinline__ ushort bf_hi(float x) {
    uint u = __float_as_uint(x);
    uint r = (u + 0x7fffu + ((u >> 16) & 1u)) >> 16;
    return (ushort)r;
}
__device__ __forceinline__ float bf_f(ushort h) {
    return __uint_as_float(((uint)h) << 16);
}

// async global->LDS 16B: per-lane global src, wave-uniform LDS base + lane*16
__device__ __forceinline__ void gload16(const void* g, void* l) {
    __builtin_amdgcn_global_load_lds((const __attribute__((address_space(1))) void*)g,
                                     (__attribute__((address_space(3))) void*)l, 16, 0, 0);
}

// ---------------------------------------------------------------------------
// split_x: fp32 -> bf16 hi/lo arrays (same layout). 4 elems/thread.
// ---------------------------------------------------------------------------
__global__ __launch_bounds__(256)
void split_x(const float* __restrict__ x, ushort* __restrict__ xh,
             ushort* __restrict__ xl)
{
    int idx = (blockIdx.x * 256 + threadIdx.x) * 4;
    float4 v = *(const float4*)&x[idx];
    float f[4] = {v.x, v.y, v.z, v.w};
    ushort h[4], l[4];
#pragma unroll
    for (int e = 0; e < 4; ++e) {
        h[e] = bf_hi(f[e]);
        l[e] = bf_hi(f[e] - bf_f(h[e]));
    }
    *(ushort4*)&xh[idx] = make_ushort4(h[0], h[1], h[2], h[3]);
    *(ushort4*)&xl[idx] = make_ushort4(l[0], l[1], l[2], l[3]);
}

// ---------------------------------------------------------------------------
// tw_prep: W [2048 k][ldw cols] fp32, cols [c0,c0+2048) -> Wt_hi/lo [n][k] bf16
// ---------------------------------------------------------------------------
__global__ __launch_bounds__(256)
void tw_prep(const float* __restrict__ W, int ldw, int c0,
             ushort* __restrict__ th, ushort* __restrict__ tl)
{
    __shared__ float tile[32][33];
    const int k0 = blockIdx.x * 32, n0 = blockIdx.y * 32;
    const int tx = threadIdx.x & 31, ty = threadIdx.x >> 5;   // 32 x 8
#pragma unroll
    for (int j = 0; j < 4; ++j)
        tile[ty + 8 * j][tx] = W[(size_t)(k0 + ty + 8 * j) * ldw + c0 + n0 + tx];
    __syncthreads();
#pragma unroll
    for (int j = 0; j < 4; ++j) {
        float v = tile[tx][ty + 8 * j];
        ushort h = bf_hi(v);
        ushort l = bf_hi(v - bf_f(h));
        size_t off = (size_t)(n0 + ty + 8 * j) * GK + k0 + tx;
        th[off] = h;
        tl[off] = l;
    }
}

// ---------------------------------------------------------------------------
// Split-bf16 MFMA GEMM (round-6 validated, unchanged).
// ---------------------------------------------------------------------------
template <int SCATTER>
__global__ __launch_bounds__(256)
void gemm_bf16(const ushort* __restrict__ Ah, const ushort* __restrict__ Al,
               const ushort* __restrict__ Bh, const ushort* __restrict__ Bl,
               float* __restrict__ out)
{
    __shared__ ushort AhS[4096], AlS[4096], BhS[4096], BlS[4096];  // [128][32] each

    const int tid  = threadIdx.x;
    const int wid  = tid >> 6;
    const int lane = tid & 63;
    const int lh   = lane >> 4;
    const int j16  = lane & 15;
    const int wm   = wid >> 1, wn = wid & 1;
    const int bm   = blockIdx.y * 128, bn = blockIdx.x * 128;

    const int g0 = wid * 128 + lane;
    const int g1 = g0 + 64;
    const int r0 = g0 >> 2, o0 = (g0 & 3) ^ (r0 & 3);
    const int r1 = g1 >> 2, o1 = (g1 & 3) ^ (r1 & 3);
    const size_t sa0 = (size_t)(bm + r0) * GK + o0 * 8;
    const size_t sa1 = (size_t)(bm + r1) * GK + o1 * 8;
    const size_t sb0 = (size_t)(bn + r0) * GK + o0 * 8;
    const size_t sb1 = (size_t)(bn + r1) * GK + o1 * 8;
    const ushort* a0h = Ah + sa0; const ushort* a1h = Ah + sa1;
    const ushort* a0l = Al + sa0; const ushort* a1l = Al + sa1;
    const ushort* b0h = Bh + sb0; const ushort* b1h = Bh + sb1;
    const ushort* b0l = Bl + sb0; const ushort* b1l = Bl + sb1;
    const int lds0 = wid * 1024;
    const int lds1 = wid * 1024 + 512;

    const int swz = (lh ^ (j16 & 3)) * 8;
    int offA[4], offB[4];
#pragma unroll
    for (int i = 0; i < 4; ++i) {
        offA[i] = (wm * 64 + i * 16 + j16) * 32 + swz;
        offB[i] = (wn * 64 + i * 16 + j16) * 32 + swz;
    }

    f32x4 acc[4][4];
#pragma unroll
    for (int i = 0; i < 4; ++i)
#pragma unroll
        for (int j = 0; j < 4; ++j)
#pragma unroll
            for (int e = 0; e < 4; ++e) acc[i][j][e] = 0.f;

    for (int kt = 0; kt < GK; kt += 32) {
        __syncthreads();
        gload16(a0h + kt, &AhS[lds0]);
        gload16(a1h + kt, &AhS[lds1]);
        gload16(a0l + kt, &AlS[lds0]);
        gload16(a1l + kt, &AlS[lds1]);
        gload16(b0h + kt, &BhS[lds0]);
        gload16(b1h + kt, &BhS[lds1]);
        gload16(b0l + kt, &BlS[lds0]);
        gload16(b1l + kt, &BlS[lds1]);
        __syncthreads();

        bf16x8 ah[4], al[4], bh[4], bl[4];
#pragma unroll
        for (int i = 0; i < 4; ++i) {
            ah[i] = *(const bf16x8*)&AhS[offA[i]];
            al[i] = *(const bf16x8*)&AlS[offA[i]];
            bh[i] = *(const bf16x8*)&BhS[offB[i]];
            bl[i] = *(const bf16x8*)&BlS[offB[i]];
        }
#pragma unroll
        for (int i = 0; i < 4; ++i)
#pragma unroll
            for (int j = 0; j < 4; ++j) {
                acc[i][j] = MFMA16(ah[i], bh[j], acc[i][j]);
                acc[i][j] = MFMA16(ah[i], bl[j], acc[i][j]);
                acc[i][j] = MFMA16(al[i], bh[j], acc[i][j]);
            }
    }

#pragma unroll
    for (int i = 0; i < 4; ++i)
#pragma unroll
        for (int j = 0; j < 4; ++j) {
            const int n = bn + wn * 64 + j * 16 + j16;
#pragma unroll
            for (int e = 0; e < 4; ++e) {
                const int m = bm + wm * 64 + i * 16 + 4 * lh + e;
                if (SCATTER) {
                    const int h = n >> 7, d = n & 127;
                    const int b = m >> 11, t = m & 2047;
                    out[(((size_t)b * NH + h) * TT + t) * HD + d] = acc[i][j][e];
                } else {
                    out[(size_t)m * EE + n] = acc[i][j][e];
                }
            }
        }
}

// ---------------------------------------------------------------------------
// RoPE: q fp32 in-place; k fp32 -> rotated bf16 hi/lo (KH/KL, same layout).
// ---------------------------------------------------------------------------
__global__ __launch_bounds__(256)
void rope_split(float* __restrict__ q, const float* __restrict__ k,
                ushort* __restrict__ kh, ushort* __restrict__ kl)
{
    int idx = blockIdx.x * 256 + threadIdx.x;
    int j = idx & 63;
    int row = idx >> 6;
    int t = row & (TT - 1);
    float inv = __expf((float)(2 * j) * (-9.210340371976184f / 128.0f));
    float ang = (float)t * inv;
    float s, c;
    sincosf(ang, &s, &c);
    size_t base = (size_t)row * HD;
    float q0 = q[base + j], q1 = q[base + j + 64];
    q[base + j]      = q0 * c - q1 * s;
    q[base + j + 64] = q1 * c + q0 * s;
    float k0 = k[base + j], k1 = k[base + j + 64];
    float ka = k0 * c - k1 * s;
    float kb = k1 * c + k0 * s;
    ushort ha = bf_hi(ka), hb = bf_hi(kb);
    kh[base + j]      = ha;  kl[base + j]      = bf_hi(ka - bf_f(ha));
    kh[base + j + 64] = hb;  kl[base + j + 64] = bf_hi(kb - bf_f(hb));
}

// ---------------------------------------------------------------------------
// Transpose+split V [B,H,T,128] fp32 -> VtH/VtL [B,H,128,T] bf16.
// ---------------------------------------------------------------------------
__global__ __launch_bounds__(256)
void transpose_split(const float* __restrict__ v, ushort* __restrict__ vth,
                     ushort* __restrict__ vtl)
{
    __shared__ float tile[32][33];
    const int bh = blockIdx.z;
    const int t0 = blockIdx.x * 32, d0 = blockIdx.y * 32;
    const int tx = threadIdx.x & 31, ty = threadIdx.x >> 5;
#pragma unroll
    for (int j = 0; j < 4; ++j)
        tile[ty + 8 * j][tx] = v[((size_t)bh * TT + t0 + ty + 8 * j) * HD + d0 + tx];
    __syncthreads();
#pragma unroll
    for (int j = 0; j < 4; ++j) {
        float val = tile[tx][ty + 8 * j];
        size_t off = ((size_t)bh * HD + d0 + ty + 8 * j) * TT + t0 + tx;
        ushort h = bf_hi(val);
        vth[off] = h;
        vtl[off] = bf_hi(val - bf_f(h));
    }
}

// ---------------------------------------------------------------------------
// MFMA flash attention v3: = v2 (round-9 measured correct) + schedule fixes.
//  (a) Double-buffered K/V LDS (129 KB), staging for tile t+1 issued at the
//      TOP of tile t -> the compiler's vmcnt(0) drain at the mid-tile barrier
//      gives loads the whole QK+softmax phase to fly. Plain __syncthreads.
//  (b) Complementary-qt pairing: block handles q-tile p then 15-p -> uniform
//      36 tiles/block, grid 8x32 = 256 blocks = 1/CU, no tail imbalance.
//  (c) Grid-swap: bh on blockIdx.x -> linear id mod 8 = bh&7 -> the 8 blocks
//      sharing a bh land on one XCD -> K/V (2 MB/bh) L2 reuse.
// 2 barriers per 64-key tile. P aliases the CURRENT K buffer (dead after QK).
// ---------------------------------------------------------------------------
__global__ __launch_bounds__(256, 1)
void attn_mfma3(const float* __restrict__ Q,
                const ushort* __restrict__ KH, const ushort* __restrict__ KL,
                const ushort* __restrict__ VH, const ushort* __restrict__ VL,
                const int* __restrict__ am,
                ushort* __restrict__ oh, ushort* __restrict__ ol)
{
    __shared__ ushort KhS[2][8192];   // K hi [64 key][128 dim]; P hi after QK
    __shared__ ushort KlS[2][8192];   // K lo; P lo after QK
    __shared__ ushort VhS[2][8192];   // Vt hi [128 dim][64 key]
    __shared__ ushort VlS[2][8192];   // Vt lo
    __shared__ float  cor[4][32], lsum[4][32];

    const int tid  = threadIdx.x;
    const int wid  = tid >> 6;
    const int lane = tid & 63;
    const int lh   = lane >> 4;
    const int j16  = lane & 15;

    const int bh = blockIdx.x;        // 0..31 -> XCD = bh&7 (round-robin by id)
    const int pq = blockIdx.y;        // pair index 0..7
    const int bb = bh >> 4, hh = bh & 15;

    // staging per-lane constants (phys granule p -> logical row/granule)
    int krow[4], kgl[4], vrow[4], vgl[4];
#pragma unroll
    for (int j = 0; j < 4; ++j) {
        int p = wid * 256 + j * 64 + lane;
        krow[j] = p >> 4; kgl[j] = (p & 15) ^ (krow[j] & 7);
        vrow[j] = p >> 3; vgl[j] = (p & 7)  ^ (vrow[j] & 7);
    }
    const ushort* KHb = KH + (size_t)bh * TT * HD;
    const ushort* KLb = KL + (size_t)bh * TT * HD;
    const ushort* VHb = VH + (size_t)bh * HD * TT;
    const ushort* VLb = VL + (size_t)bh * HD * TT;

#define STAGE(buf, tt) do {                                                    \
    const int kv_ = (tt) * 64;                                                 \
    _Pragma("unroll")                                                          \
    for (int j = 0; j < 4; ++j) {                                              \
        const int gb = (wid * 256 + j * 64) * 8;                               \
        gload16(KHb + (size_t)(kv_ + krow[j]) * HD + kgl[j] * 8, &KhS[buf][gb]); \
        gload16(KLb + (size_t)(kv_ + krow[j]) * HD + kgl[j] * 8, &KlS[buf][gb]); \
        gload16(VHb + (size_t)vrow[j] * TT + kv_ + vgl[j] * 8,   &VhS[buf][gb]); \
        gload16(VLb + (size_t)vrow[j] * TT + kv_ + vgl[j] * 8,   &VlS[buf][gb]); \
    }                                                                          \
} while (0)

    const float scale = 0.08838834764831843f;

    for (int hf = 0; hf < 2; ++hf) {
        const int qt = hf ? (15 - pq) : pq;
        const int q0 = qt * 128;
        const int nt = 2 * qt + 2;        // always even

        // ---- Q fragments (pre-scaled), bf16 hi/lo, 2 row-groups ----
        bf16x8 qhf[2][4], qlf[2][4];
#pragma unroll
        for (int g = 0; g < 2; ++g) {
            const float* qrow = Q + ((size_t)bh * TT + q0 + wid * 32 + g * 16 + j16) * HD;
#pragma unroll
            for (int kc = 0; kc < 4; ++kc) {
                float4 a = *(const float4*)(qrow + kc * 32 + lh * 8);
                float4 b = *(const float4*)(qrow + kc * 32 + lh * 8 + 4);
                float f[8] = {a.x, a.y, a.z, a.w, b.x, b.y, b.z, b.w};
#pragma unroll
                for (int e = 0; e < 8; ++e) {
                    float x = f[e] * scale;
                    ushort hv = bf_hi(x);
                    ushort lv = bf_hi(x - bf_f(hv));
                    qhf[g][kc][e] = (short)hv;
                    qlf[g][kc][e] = (short)lv;
                }
            }
        }
        int qmk[2][4];
#pragma unroll
        for (int g = 0; g < 2; ++g)
#pragma unroll
            for (int r = 0; r < 4; ++r)
                qmk[g][r] = am[bb * TT + q0 + wid * 32 + g * 16 + 4 * lh + r];

        float m_run[2][4], l_run[2][4];
#pragma unroll
        for (int g = 0; g < 2; ++g)
#pragma unroll
            for (int r = 0; r < 4; ++r) { m_run[g][r] = -3e38f; l_run[g][r] = 0.f; }
        f32x4 acc[8][2];
#pragma unroll
        for (int dt = 0; dt < 8; ++dt)
#pragma unroll
            for (int cg = 0; cg < 2; ++cg)
#pragma unroll
                for (int e = 0; e < 4; ++e) acc[dt][cg][e] = 0.f;

        // prologue: stage tile 0 into buffer 0
        STAGE(0, 0);
        __syncthreads();   // drain: buf0 ready

        for (int t = 0; t < nt; ++t) {
            const int c = t & 1;
            if (t + 1 < nt) STAGE(c ^ 1, t + 1);   // issue-early; drained at B2
            const int kv0 = t * 64;
            int km[4];
#pragma unroll
            for (int kg = 0; kg < 4; ++kg)
                km[kg] = am[bb * TT + kv0 + kg * 16 + j16];

            // ---- QK^T on buffer c ----
            f32x4 s[2][4];
#pragma unroll
            for (int g = 0; g < 2; ++g)
#pragma unroll
                for (int kg = 0; kg < 4; ++kg)
#pragma unroll
                    for (int e = 0; e < 4; ++e) s[g][kg][e] = 0.f;
#pragma unroll
            for (int kc = 0; kc < 4; ++kc) {
#pragma unroll
                for (int kg = 0; kg < 4; ++kg) {
                    const int idx = (kg * 16 + j16) * 128 + (((kc * 4 + lh) ^ (j16 & 7)) * 8);
                    bf16x8 kh = *(const bf16x8*)&KhS[c][idx];
                    bf16x8 kl = *(const bf16x8*)&KlS[c][idx];
#pragma unroll
                    for (int g = 0; g < 2; ++g) {
                        s[g][kg] = MFMA16(qhf[g][kc], kh, s[g][kg]);
                        s[g][kg] = MFMA16(qhf[g][kc], kl, s[g][kg]);
                        s[g][kg] = MFMA16(qlf[g][kc], kh, s[g][kg]);
                    }
                }
            }

            // ---- online softmax (registers + shfl only) ----
            float pv[2][4][4], corr[2][4];
#pragma unroll
            for (int g = 0; g < 2; ++g)
#pragma unroll
                for (int r = 0; r < 4; ++r) {
                    const int qg = q0 + wid * 32 + g * 16 + 4 * lh + r;
                    float x[4];
                    float tmax = -3e38f;
#pragma unroll
                    for (int kg = 0; kg < 4; ++kg) {
                        const int key = kv0 + kg * 16 + j16;
                        float xx = s[g][kg][r];
                        if ((key > qg) | (km[kg] == 0) | (qmk[g][r] == 0)) xx = -1e9f;
                        x[kg] = xx;
                        tmax = fmaxf(tmax, xx);
                    }
                    tmax = fmaxf(tmax, __shfl_xor(tmax, 1));
                    tmax = fmaxf(tmax, __shfl_xor(tmax, 2));
                    tmax = fmaxf(tmax, __shfl_xor(tmax, 4));
                    tmax = fmaxf(tmax, __shfl_xor(tmax, 8));
                    float mnew = fmaxf(m_run[g][r], tmax);
                    corr[g][r] = __expf(m_run[g][r] - mnew);
                    m_run[g][r] = mnew;
                    float psum = 0.f;
#pragma unroll
                    for (int kg = 0; kg < 4; ++kg) {
                        pv[g][r][kg] = __expf(x[kg] - mnew);
                        psum += pv[g][r][kg];
                    }
                    psum += __shfl_xor(psum, 1);
                    psum += __shfl_xor(psum, 2);
                    psum += __shfl_xor(psum, 4);
                    psum += __shfl_xor(psum, 8);
                    l_run[g][r] = l_run[g][r] * corr[g][r] + psum;
                    if (j16 == 0) cor[wid][g * 16 + 4 * lh + r] = corr[g][r];
                }

            __syncthreads();   // B2: QK reads of buf c done; also drains t+1 loads

            // ---- P -> bf16 hi/lo into per-wave chunk of KhS[c]/KlS[c] ----
            ushort* PH = &KhS[c][wid * 2048];
            ushort* PL = &KlS[c][wid * 2048];
#pragma unroll
            for (int g = 0; g < 2; ++g)
#pragma unroll
                for (int r = 0; r < 4; ++r) {
                    const int q = g * 16 + 4 * lh + r;
#pragma unroll
                    for (int kg = 0; kg < 4; ++kg) {
                        const int glog = kg * 2 + (j16 >> 3);
                        const int idx = q * 64 + ((glog ^ (q & 7)) * 8) + (j16 & 7);
                        float p = pv[g][r][kg];
                        ushort h = bf_hi(p);
                        PH[idx] = h;
                        PL[idx] = bf_hi(p - bf_f(h));
                    }
                }

            // ---- rescale O^T (intra-wave cor) ----
            const float cq0 = cor[wid][j16];
            const float cq1 = cor[wid][16 + j16];
#pragma unroll
            for (int dt = 0; dt < 8; ++dt)
#pragma unroll
                for (int e = 0; e < 4; ++e) {
                    acc[dt][0][e] *= cq0;
                    acc[dt][1][e] *= cq1;
                }

            // ---- PV: O^T += Vt * P^T on buffer c ----
#pragma unroll
            for (int cc = 0; cc < 2; ++cc) {
                bf16x8 pbh0, pbl0, pbh1, pbl1;
                {
                    const int p0 = (j16) * 64 + (((cc * 4 + lh) ^ (j16 & 7)) * 8);
                    const int p1 = (16 + j16) * 64 + (((cc * 4 + lh) ^ (j16 & 7)) * 8);
                    pbh0 = *(const bf16x8*)&PH[p0];
                    pbl0 = *(const bf16x8*)&PL[p0];
                    pbh1 = *(const bf16x8*)&PH[p1];
                    pbl1 = *(const bf16x8*)&PL[p1];
                }
#pragma unroll
                for (int dt = 0; dt < 8; ++dt) {
                    const int vidx = (dt * 16 + j16) * 64 + (((cc * 4 + lh) ^ (j16 & 7)) * 8);
                    bf16x8 vh = *(const bf16x8*)&VhS[c][vidx];
                    bf16x8 vl = *(const bf16x8*)&VlS[c][vidx];
                    acc[dt][0] = MFMA16(vh, pbh0, acc[dt][0]);
                    acc[dt][0] = MFMA16(vh, pbl0, acc[dt][0]);
                    acc[dt][0] = MFMA16(vl, pbh0, acc[dt][0]);
                    acc[dt][1] = MFMA16(vh, pbh1, acc[dt][1]);
                    acc[dt][1] = MFMA16(vh, pbl1, acc[dt][1]);
                    acc[dt][1] = MFMA16(vl, pbh1, acc[dt][1]);
                }
            }
            __syncthreads();   // B3: buf c fully consumed; next iter may restage it
        }

        // ---- epilogue for this q-tile: 1/l, store bf16 hi/lo [B,T,E] ----
        if (j16 == 0) {
#pragma unroll
            for (int g = 0; g < 2; ++g)
#pragma unroll
                for (int r = 0; r < 4; ++r)
                    lsum[wid][g * 16 + 4 * lh + r] = l_run[g][r];
        }
#pragma unroll
        for (int cg = 0; cg < 2; ++cg) {
            const float lv = lsum[wid][cg * 16 + j16];
            const float linv = (lv > 0.f) ? (1.f / lv) : 0.f;
            const int qg = q0 + wid * 32 + cg * 16 + j16;
            const size_t ob = ((size_t)bb * TT + qg) * EE + hh * HD;
#pragma unroll
            for (int dt = 0; dt < 8; ++dt) {
                ushort h[4], l[4];
#pragma unroll
                for (int e = 0; e < 4; ++e) {
                    float v = acc[dt][cg][e] * linv;
                    h[e] = bf_hi(v);
                    l[e] = bf_hi(v - bf_f(h[e]));
                }
                *(ushort4*)&oh[ob + dt * 16 + 4 * lh] = make_ushort4(h[0], h[1], h[2], h[3]);
                *(ushort4*)&ol[ob + dt * 16 + 4 * lh] = make_ushort4(l[0], l[1], l[2], l[3]);
            }
        }
    }
#undef STAGE
}

// ---------------------------------------------------------------------------
extern "C" void kernel_launch(void* const* d_in, const int* in_sizes, int n_in,
                              void* d_out, int out_size, void* d_ws, size_t ws_size,
                              hipStream_t stream)
{
    (void)in_sizes; (void)n_in; (void)out_size; (void)ws_size;
    const float* x     = (const float*)d_in[0];
    const int*   amask = (const int*)d_in[1];
    const float* Wqkv  = (const float*)d_in[2];
    const float* Wproj = (const float*)d_in[3];
    float* out = (float*)d_out;

    char* ws = (char*)d_ws;
    const size_t MB = 1024 * 1024;
    // Workspace schedule (144 MB, proven in rounds 6/9):
    //  [0,32)   q fp32 (rope'd in place)
    //  [32,64)  k fp32 -> dead after rope -> VtH@32, VtL@48 (bf16)
    //  [64,96)  v fp32 -> dead after transpose -> ah@64, al@80 (bf16)
    //  [96,128) xh/xl  -> dead after QKV gemms -> KH@96, KL@112 (bf16)
    //  [128,144) wth/wtl (per-slice transposed weights)
    float*  q   = (float*)(ws + 0 * MB);
    float*  k   = (float*)(ws + 32 * MB);
    float*  v   = (float*)(ws + 64 * MB);
    ushort* vth = (ushort*)(ws + 32 * MB);
    ushort* vtl = (ushort*)(ws + 48 * MB);
    ushort* ah  = (ushort*)(ws + 64 * MB);
    ushort* al  = (ushort*)(ws + 80 * MB);
    ushort* xh  = (ushort*)(ws + 96 * MB);
    ushort* xl  = (ushort*)(ws + 112 * MB);
    ushort* kh  = (ushort*)(ws + 96 * MB);
    ushort* kl  = (ushort*)(ws + 112 * MB);
    ushort* wth = (ushort*)(ws + 128 * MB);
    ushort* wtl = (ushort*)(ws + 136 * MB);

    // 1) x -> bf16 hi/lo
    split_x<<<(MM * EE) / (256 * 4), 256, 0, stream>>>(x, xh, xl);

    // 2) per-slice: transpose+split weight, then MFMA GEMM -> q/k/v fp32
    float* qkv[3] = {q, k, v};
    for (int s = 0; s < 3; ++s) {
        tw_prep<<<dim3(GK / 32, EE / 32), 256, 0, stream>>>(
            Wqkv, 3 * EE, s * EE, wth, wtl);
        gemm_bf16<1><<<dim3(EE / 128, MM / 128), 256, 0, stream>>>(
            xh, xl, wth, wtl, qkv[s]);
    }

    // 3) RoPE: q in place; k -> KH/KL bf16 (xh/xl dead)
    rope_split<<<(MM * NH * 64) / 256, 256, 0, stream>>>(q, k, kh, kl);

    // 4) V -> VtH/VtL bf16 [B,H,128,T] (k dead)
    transpose_split<<<dim3(TT / 32, HD / 32, 2 * NH), 256, 0, stream>>>(v, vth, vtl);

    // 5) proj weight prep
    tw_prep<<<dim3(GK / 32, EE / 32), 256, 0, stream>>>(Wproj, EE, 0, wth, wtl);

    // 6) attention -> bf16 hi/lo (v dead). Grid: bh on x (XCD clustering),
    //    pair on y; each block does q-tiles (pq, 15-pq) = uniform 36 tiles.
    attn_mfma3<<<dim3(2 * NH, 8), 256, 0, stream>>>(
        q, kh, kl, vth, vtl, amask, ah, al);

    // 7) out projection
    gemm_bf16<0><<<dim3(EE / 128, MM / 128), 256, 0, stream>>>(
        ah, al, wth, wtl, out);
}